// Round 1
// baseline (2124.902 us; speedup 1.0000x reference)
//
#include <hip/hip_runtime.h>
#include <hip/hip_bf16.h>
#include <math.h>

// Problem constants (from reference)
#define PN0 585728
#define PN1 22528
#define PN2 2048
#define PE1 563200
#define PE2 20480
#define IN_C 602
#define HID 256
#define OUT_C 41

// ---------------- workspace layout ----------------
constexpr size_t wal(size_t x) { return (x + 255) & ~(size_t)255; }
constexpr size_t OFF_CNT1    = 0;
constexpr size_t OFF_CNT2    = OFF_CNT1    + wal((size_t)PN1 * 4);
constexpr size_t OFF_ROWPTR1 = OFF_CNT2    + wal((size_t)PN2 * 4);   // memset covers [0, OFF_ROWPTR1)
constexpr size_t OFF_CURSOR1 = OFF_ROWPTR1 + wal((size_t)(PN1 + 1) * 4);
constexpr size_t OFF_ROWPTR2 = OFF_CURSOR1 + wal((size_t)PN1 * 4);
constexpr size_t OFF_CURSOR2 = OFF_ROWPTR2 + wal((size_t)(PN2 + 1) * 4);
constexpr size_t OFF_CSR1    = OFF_CURSOR2 + wal((size_t)PN2 * 4);
constexpr size_t OFF_CSR2    = OFF_CSR1    + wal((size_t)PE1 * 4);
constexpr size_t OFF_AGG1    = OFF_CSR2    + wal((size_t)PE2 * 4);
constexpr size_t OFF_H       = OFF_AGG1    + wal((size_t)PN1 * IN_C * 4);
constexpr size_t OFF_AGG2    = OFF_H       + wal((size_t)PN1 * HID * 4);
constexpr size_t WS_NEEDED   = OFF_AGG2    + wal((size_t)PN2 * HID * 4);

// ---------------- CSR build ----------------
__global__ void count_edges(const int* __restrict__ ei, int E, int* __restrict__ cnt) {
    int e = blockIdx.x * blockDim.x + threadIdx.x;
    if (e < E) atomicAdd(&cnt[ei[E + e]], 1);
}

// single-block exclusive scan (n is a multiple of 1024 here, but handles any n)
__global__ void exscan_kernel(const int* __restrict__ cnt, int* __restrict__ rowptr,
                              int* __restrict__ cursor, int n) {
    __shared__ int buf[1024];
    __shared__ int carry_s;
    int tid = threadIdx.x;
    if (tid == 0) carry_s = 0;
    __syncthreads();
    for (int base = 0; base < n; base += 1024) {
        int i = base + tid;
        int v = (i < n) ? cnt[i] : 0;
        buf[tid] = v;
        __syncthreads();
        for (int off = 1; off < 1024; off <<= 1) {
            int t = (tid >= off) ? buf[tid - off] : 0;
            __syncthreads();
            buf[tid] += t;
            __syncthreads();
        }
        int excl = buf[tid] - v + carry_s;
        if (i < n) { rowptr[i] = excl; cursor[i] = excl; }
        __syncthreads();
        if (tid == 1023) carry_s += buf[1023];
        __syncthreads();
    }
    if (tid == 0) rowptr[n] = carry_s;
}

__global__ void fill_csr(const int* __restrict__ ei, int E, int* __restrict__ cursor,
                         int* __restrict__ csr) {
    int e = blockIdx.x * blockDim.x + threadIdx.x;
    if (e < E) {
        int s = ei[e], d = ei[E + e];
        int p = atomicAdd(&cursor[d], 1);
        csr[p] = s;
    }
}

// ---------------- layer 1 aggregate: mean of gathered x rows ----------------
// one block (256 thr) per target; dims: [tid], [256+tid], [512+tid (tid<90)]
__global__ __launch_bounds__(256) void aggregate1(const float* __restrict__ x,
        const int* __restrict__ csr, const int* __restrict__ rowptr,
        float* __restrict__ agg) {
    int t = blockIdx.x;
    int tid = threadIdx.x;
    int r0 = rowptr[t], r1 = rowptr[t + 1];
    float a0 = 0.f, a1 = 0.f, a2 = 0.f;
    int j = r0;
    for (; j + 1 < r1; j += 2) {
        const float* p0 = x + (size_t)csr[j] * IN_C;
        const float* p1 = x + (size_t)csr[j + 1] * IN_C;
        float v00 = p0[tid], v01 = p0[256 + tid];
        float v10 = p1[tid], v11 = p1[256 + tid];
        float v02 = 0.f, v12 = 0.f;
        if (tid < IN_C - 512) { v02 = p0[512 + tid]; v12 = p1[512 + tid]; }
        a0 += v00 + v10; a1 += v01 + v11; a2 += v02 + v12;
    }
    if (j < r1) {
        const float* p0 = x + (size_t)csr[j] * IN_C;
        a0 += p0[tid]; a1 += p0[256 + tid];
        if (tid < IN_C - 512) a2 += p0[512 + tid];
    }
    float inv = 1.f / fmaxf((float)(r1 - r0), 1.f);
    float* o = agg + (size_t)t * IN_C;
    o[tid] = a0 * inv;
    o[256 + tid] = a1 * inv;
    if (tid < IN_C - 512) o[512 + tid] = a2 * inv;
}

// ---------------- layer 1 GEMM: h = relu(agg@Wl1 + x_dst@Wr1 + b) ----------------
// 64x64 tile per block, 256 threads, 4x4 per thread, K runs twice over 602.
__global__ __launch_bounds__(256) void gemm1(const float* __restrict__ agg,
        const float* __restrict__ x, const float* __restrict__ Wl,
        const float* __restrict__ Wr, const float* __restrict__ bias,
        float* __restrict__ h) {
    __shared__ __align__(16) float As[16 * 64];  // [k][m]
    __shared__ __align__(16) float Bs[16 * 64];  // [k][n]
    const int t = threadIdx.x;
    const int tx = t & 15, ty = t >> 4;
    const int bm = blockIdx.x * 64, bn = blockIdx.y * 64;
    const int mA = t >> 2, kA0 = (t & 3) * 4;    // A tile: 64 rows x 16 k
    const int kB = t >> 4, nB0 = (t & 15) * 4;   // B tile: 16 k x 64 n
    float acc[4][4] = {};
    for (int phase = 0; phase < 2; ++phase) {
        const float* A = phase ? x : agg;
        const float* B = phase ? Wr : Wl;
        const float* Arow = A + (size_t)(bm + mA) * IN_C;
        for (int k0 = 0; k0 < IN_C; k0 += 16) {
            __syncthreads();
            #pragma unroll
            for (int jj = 0; jj < 4; ++jj) {
                int k = k0 + kA0 + jj;
                As[(kA0 + jj) * 64 + mA] = (k < IN_C) ? Arow[k] : 0.f;
            }
            {
                int k = k0 + kB;
                float4 bv = make_float4(0.f, 0.f, 0.f, 0.f);
                if (k < IN_C) bv = *(const float4*)(B + (size_t)k * HID + bn + nB0);
                *(float4*)(Bs + kB * 64 + nB0) = bv;
            }
            __syncthreads();
            #pragma unroll
            for (int kk = 0; kk < 16; ++kk) {
                float4 av = ((const float4*)As)[kk * 16 + ty];
                float4 bv = ((const float4*)Bs)[kk * 16 + tx];
                float a_[4] = {av.x, av.y, av.z, av.w};
                float b_[4] = {bv.x, bv.y, bv.z, bv.w};
                #pragma unroll
                for (int i = 0; i < 4; ++i)
                    #pragma unroll
                    for (int jc = 0; jc < 4; ++jc)
                        acc[i][jc] += a_[i] * b_[jc];
            }
        }
    }
    #pragma unroll
    for (int i = 0; i < 4; ++i) {
        int row = bm + ty * 4 + i;
        float4 r;
        r.x = fmaxf(acc[i][0] + bias[bn + tx * 4 + 0], 0.f);
        r.y = fmaxf(acc[i][1] + bias[bn + tx * 4 + 1], 0.f);
        r.z = fmaxf(acc[i][2] + bias[bn + tx * 4 + 2], 0.f);
        r.w = fmaxf(acc[i][3] + bias[bn + tx * 4 + 3], 0.f);
        *(float4*)(h + (size_t)row * HID + bn + tx * 4) = r;
    }
}

// ---------------- layer 2 aggregate ----------------
__global__ __launch_bounds__(256) void aggregate2(const float* __restrict__ h,
        const int* __restrict__ csr, const int* __restrict__ rowptr,
        float* __restrict__ agg2) {
    int t = blockIdx.x, tid = threadIdx.x;
    int r0 = rowptr[t], r1 = rowptr[t + 1];
    float a = 0.f;
    int j = r0;
    for (; j + 1 < r1; j += 2)
        a += h[(size_t)csr[j] * HID + tid] + h[(size_t)csr[j + 1] * HID + tid];
    if (j < r1) a += h[(size_t)csr[j] * HID + tid];
    agg2[(size_t)t * HID + tid] = a / fmaxf((float)(r1 - r0), 1.f);
}

// ---------------- layer 2 GEMM + log_softmax: one wave per row ----------------
__global__ __launch_bounds__(256) void gemm2_lsm(const float* __restrict__ agg2,
        const float* __restrict__ h, const float* __restrict__ Wl,
        const float* __restrict__ Wr, const float* __restrict__ bias,
        float* __restrict__ out) {
    int lane = threadIdx.x & 63;
    int row = blockIdx.x * 4 + (threadIdx.x >> 6);
    const float* a = agg2 + (size_t)row * HID;
    const float* hr = h + (size_t)row * HID;
    float acc = 0.f;
    if (lane < OUT_C) {
        acc = bias[lane];
        for (int k = 0; k < HID; ++k)
            acc += a[k] * Wl[k * OUT_C + lane] + hr[k] * Wr[k * OUT_C + lane];
    }
    float v = (lane < OUT_C) ? acc : -1e30f;
    for (int off = 32; off > 0; off >>= 1) v = fmaxf(v, __shfl_down(v, off));
    float mx = __shfl(v, 0);
    float e = (lane < OUT_C) ? expf(acc - mx) : 0.f;
    for (int off = 32; off > 0; off >>= 1) e += __shfl_down(e, off);
    float s = __shfl(e, 0);
    if (lane < OUT_C) out[(size_t)row * OUT_C + lane] = acc - mx - logf(s);
}

extern "C" void kernel_launch(void* const* d_in, const int* in_sizes, int n_in,
                              void* d_out, int out_size, void* d_ws, size_t ws_size,
                              hipStream_t stream) {
    const float* x   = (const float*)d_in[0];
    const int*   ei1 = (const int*)d_in[1];
    const int*   ei2 = (const int*)d_in[2];
    const float* Wl1 = (const float*)d_in[3];
    const float* bl1 = (const float*)d_in[4];
    const float* Wr1 = (const float*)d_in[5];
    const float* Wl2 = (const float*)d_in[6];
    const float* bl2 = (const float*)d_in[7];
    const float* Wr2 = (const float*)d_in[8];
    float* out = (float*)d_out;

    char* ws = (char*)d_ws;
    int* cnt1    = (int*)(ws + OFF_CNT1);
    int* cnt2    = (int*)(ws + OFF_CNT2);
    int* rowptr1 = (int*)(ws + OFF_ROWPTR1);
    int* cursor1 = (int*)(ws + OFF_CURSOR1);
    int* rowptr2 = (int*)(ws + OFF_ROWPTR2);
    int* cursor2 = (int*)(ws + OFF_CURSOR2);
    int* csr1    = (int*)(ws + OFF_CSR1);
    int* csr2    = (int*)(ws + OFF_CSR2);
    float* agg1  = (float*)(ws + OFF_AGG1);
    float* h     = (float*)(ws + OFF_H);
    float* agg2  = (float*)(ws + OFF_AGG2);

    // zero the degree counters (ws is poisoned 0xAA before every call)
    hipMemsetAsync(ws, 0, OFF_ROWPTR1, stream);

    count_edges<<<(PE1 + 255) / 256, 256, 0, stream>>>(ei1, PE1, cnt1);
    count_edges<<<(PE2 + 255) / 256, 256, 0, stream>>>(ei2, PE2, cnt2);
    exscan_kernel<<<1, 1024, 0, stream>>>(cnt1, rowptr1, cursor1, PN1);
    exscan_kernel<<<1, 1024, 0, stream>>>(cnt2, rowptr2, cursor2, PN2);
    fill_csr<<<(PE1 + 255) / 256, 256, 0, stream>>>(ei1, PE1, cursor1, csr1);
    fill_csr<<<(PE2 + 255) / 256, 256, 0, stream>>>(ei2, PE2, cursor2, csr2);

    aggregate1<<<PN1, 256, 0, stream>>>(x, csr1, rowptr1, agg1);
    gemm1<<<dim3(PN1 / 64, HID / 64), 256, 0, stream>>>(agg1, x, Wl1, Wr1, bl1, h);
    aggregate2<<<PN2, 256, 0, stream>>>(h, csr2, rowptr2, agg2);
    gemm2_lsm<<<PN2 / 4, 256, 0, stream>>>(agg2, h, Wl2, Wr2, bl2, out);
}